// Round 1
// baseline (495.100 us; speedup 1.0000x reference)
//
#include <hip/hip_runtime.h>

// HierarchicalMemory: Hebbian update (rank-1 + clamp + block-triangular mask)
// fused with 5 masked attractor-retrieval GEMV iterations.
//
// Key structure:
//   M[p,q] = clip(FORGET*M_prev[p,q] + (LR*a[p])*b[q], -1, 1) * hier_mask[p,q]
//   hier_mask: row p (stream r) has nonzero cols only q >= idx[r]
//   iteration t updates only rows p < Rt[t] = {400,340,280,200,100}
// M is never written out -> recompute from M_prev each iteration; only the
// masked suffix of each row is ever loaded (198 MB total footprint < 256 MB L3,
// so iterations 1..4 re-read from Infinity Cache).

#define PDIM 400
#define FORGET 0.9999f
#define LRATE  0.5f
#define DECAY  0.8f
#define SLOPE  0.01f

__device__ __forceinline__ float leaky_clip(float x) {
    x = fminf(fmaxf(x, -1.0f), 1.0f);
    return x > 0.0f ? x : SLOPE * x;
}

__device__ __forceinline__ float clamp1(float x) {
    return fminf(fmaxf(x, -1.0f), 1.0f);
}

__global__ __launch_bounds__(512, 4)
void hier_mem_kernel(const float* __restrict__ M_prev,
                     const float* __restrict__ p_inf,
                     const float* __restrict__ p_gen,
                     const float* __restrict__ query,
                     float* __restrict__ out)
{
    __shared__ float s_h[2][PDIM];   // double-buffered h
    __shared__ float s_b[PDIM];      // b[q] = p_inf[q] + p_gen[q]
    __shared__ float s_la[PDIM];     // la[p] = LR * (p_inf[p] - p_gen[p])

    const int b   = blockIdx.x;
    const int tid = threadIdx.x;
    const float* __restrict__ Mb = M_prev + (size_t)b * PDIM * PDIM;

    if (tid < PDIM) {
        const float pi = p_inf[b * PDIM + tid];
        const float pg = p_gen[b * PDIM + tid];
        s_la[tid]   = LRATE * (pi - pg);
        s_b[tid]    = pi + pg;
        s_h[0][tid] = leaky_clip(query[b * PDIM + tid]);
    }
    __syncthreads();

    const int group  = tid >> 4;   // 0..31 (16-lane sub-groups, wave-aligned)
    const int lane16 = tid & 15;

    // active-row counts per iteration (streams freeze progressively)
    const int Rt[5] = {400, 340, 280, 200, 100};

    int cur = 0;
    #pragma unroll
    for (int t = 0; t < 5; ++t) {
        const int R = Rt[t];
        const float* __restrict__ h_old = s_h[cur];
        float* __restrict__ h_new = s_h[cur ^ 1];

        for (int p = group; p < R; p += 32) {
            // first nonzero column of row p (hier_mask block boundary)
            const int cbeg = (p < 100) ? 0 : (p < 200) ? 100 :
                             (p < 280) ? 200 : (p < 340) ? 280 : 340;
            const int nf4 = (PDIM - cbeg) >> 2;   // widths all divisible by 4
            const float la = s_la[p];

            const float4* __restrict__ rowp = (const float4*)(Mb + (size_t)p * PDIM + cbeg);
            const float4* __restrict__ hb4  = (const float4*)(h_old + cbeg);
            const float4* __restrict__ bb4  = (const float4*)(s_b + cbeg);

            float acc = 0.0f;
            for (int j = lane16; j < nf4; j += 16) {
                const float4 mp = rowp[j];
                const float4 hv = hb4[j];
                const float4 bv = bb4[j];
                const float m0 = clamp1(fmaf(FORGET, mp.x, la * bv.x));
                const float m1 = clamp1(fmaf(FORGET, mp.y, la * bv.y));
                const float m2 = clamp1(fmaf(FORGET, mp.z, la * bv.z));
                const float m3 = clamp1(fmaf(FORGET, mp.w, la * bv.w));
                acc = fmaf(m0, hv.x, acc);
                acc = fmaf(m1, hv.y, acc);
                acc = fmaf(m2, hv.z, acc);
                acc = fmaf(m3, hv.w, acc);
            }
            // 16-lane tree reduction (groups are 16-aligned within the wave)
            acc += __shfl_xor(acc, 1, 64);
            acc += __shfl_xor(acc, 2, 64);
            acc += __shfl_xor(acc, 4, 64);
            acc += __shfl_xor(acc, 8, 64);

            if (lane16 == 0) {
                h_new[p] = leaky_clip(fmaf(DECAY, h_old[p], acc));
            }
        }

        // frozen rows carry through unchanged
        if (tid >= R && tid < PDIM) {
            h_new[tid] = h_old[tid];
        }
        __syncthreads();
        cur ^= 1;
    }

    if (tid < PDIM) {
        out[b * PDIM + tid] = s_h[cur][tid];
    }
}

extern "C" void kernel_launch(void* const* d_in, const int* in_sizes, int n_in,
                              void* d_out, int out_size, void* d_ws, size_t ws_size,
                              hipStream_t stream) {
    const float* M_prev = (const float*)d_in[0];
    const float* p_inf  = (const float*)d_in[1];
    const float* p_gen  = (const float*)d_in[2];
    const float* query  = (const float*)d_in[3];
    float* out = (float*)d_out;

    const int B = in_sizes[1] / PDIM;   // 512
    hipLaunchKernelGGL(hier_mem_kernel, dim3(B), dim3(512), 0, stream,
                       M_prev, p_inf, p_gen, query, out);
}

// Round 2
// 494.217 us; speedup vs baseline: 1.0018x; 1.0018x over previous
//
#include <hip/hip_runtime.h>

// HierarchicalMemory v2: wave-per-row streaming GEMV.
//   M[p,q] = clip(F*Mp[p,q] + (LR*a[p])*b[q], -1, 1), masked block-triangular;
//   5 attractor iterations with progressively frozen rows Rt={400,340,280,200,100}.
// Lane l of each wave owns columns [4l..4l+3] and [256+4l..256+4l+3]:
// h and b live in registers, M-row chunks are 2 coalesced predicated float4
// loads, the dot-reduce is 6 DPP adds on the VALU pipe (no LDS, no ds_swizzle).
// One batch per 512-thread block; 2 blocks/CU resident (VGPR<=128 via
// __launch_bounds__(512,4)) for latency hiding; 1-row-ahead manual prefetch.

#define PDIM 400
#define FORGET 0.9999f
#define LRATE  0.5f
#define DECAY  0.8f
#define SLOPE  0.01f

__device__ __forceinline__ float leaky_clip(float x) {
    x = fminf(fmaxf(x, -1.0f), 1.0f);
    return x > 0.0f ? x : SLOPE * x;
}
__device__ __forceinline__ float clamp1(float x) {
    return fminf(fmaxf(x, -1.0f), 1.0f);
}

// first masked f4-chunk of row p (chunk = 4-float column group)
__device__ __forceinline__ int c4beg(int p) {
    return (p < 100) ? 0 : (p < 200) ? 25 : (p < 280) ? 50 : (p < 340) ? 70 : 85;
}

// wave64 sum via DPP: stays on the VALU pipe (no ds_swizzle / LDS traffic).
// quad xor1, xor2, half-mirror (xor4), mirror (xor8), bcast15, bcast31 -> lane63.
__device__ __forceinline__ float wave_sum(float x) {
    x += __int_as_float(__builtin_amdgcn_update_dpp(0, __float_as_int(x), 0xB1,  0xf, 0xf, true));
    x += __int_as_float(__builtin_amdgcn_update_dpp(0, __float_as_int(x), 0x4E,  0xf, 0xf, true));
    x += __int_as_float(__builtin_amdgcn_update_dpp(0, __float_as_int(x), 0x141, 0xf, 0xf, true));
    x += __int_as_float(__builtin_amdgcn_update_dpp(0, __float_as_int(x), 0x140, 0xf, 0xf, true));
    x += __int_as_float(__builtin_amdgcn_update_dpp(0, __float_as_int(x), 0x142, 0xf, 0xf, true));
    x += __int_as_float(__builtin_amdgcn_update_dpp(0, __float_as_int(x), 0x143, 0xf, 0xf, true));
    return __int_as_float(__builtin_amdgcn_readlane(__float_as_int(x), 63));
}

__global__ __launch_bounds__(512, 4)
void hier_mem_kernel(const float* __restrict__ M_prev,
                     const float* __restrict__ p_inf,
                     const float* __restrict__ p_gen,
                     const float* __restrict__ query,
                     float* __restrict__ out)
{
    __shared__ float s_h[2][PDIM];
    __shared__ float s_la[PDIM];

    const int b   = blockIdx.x;
    const int tid = threadIdx.x;
    const int l   = tid & 63;   // lane
    const int wid = tid >> 6;   // wave 0..7
    const float* __restrict__ Mb = M_prev + (size_t)b * PDIM * PDIM;

    if (tid < PDIM) {
        const float pi = p_inf[b * PDIM + tid];
        const float pg = p_gen[b * PDIM + tid];
        s_la[tid]   = LRATE * (pi - pg);
        s_h[0][tid] = leaky_clip(query[b * PDIM + tid]);
    }

    // register-resident b for this lane's fixed columns
    const float4 z4 = make_float4(0.f, 0.f, 0.f, 0.f);
    const float4* __restrict__ pi4 = (const float4*)(p_inf + (size_t)b * PDIM);
    const float4* __restrict__ pg4 = (const float4*)(p_gen + (size_t)b * PDIM);
    float4 bA, bB = z4;
    {
        const float4 x = pi4[l], y = pg4[l];
        bA = make_float4(x.x + y.x, x.y + y.y, x.z + y.z, x.w + y.w);
        if (l < 36) {
            const float4 u = pi4[64 + l], v = pg4[64 + l];
            bB = make_float4(u.x + v.x, u.y + v.y, u.z + v.z, u.w + v.w);
        }
    }
    __syncthreads();

    const int Rt[5] = {400, 340, 280, 200, 100};
    int cur = 0;

    #pragma unroll
    for (int t = 0; t < 5; ++t) {
        const int R = Rt[t];
        const float* __restrict__ hcur = s_h[cur];
        float* __restrict__ hnew = s_h[cur ^ 1];

        // refresh register h (stable since last barrier)
        float4 hA = *(const float4*)(hcur + 4 * l);
        float4 hB = z4;
        if (l < 36) hB = *(const float4*)(hcur + 256 + 4 * l);

        // wave-per-row, 1-row-ahead prefetch
        int p = wid;
        int c4 = 0;
        float4 cA = z4, cB = z4;
        if (p < R) {
            c4 = c4beg(p);
            const float* __restrict__ row = Mb + (size_t)p * PDIM;
            if (l >= c4)               cA = *(const float4*)(row + 4 * l);
            if (l < 36 && 64 + l >= c4) cB = *(const float4*)(row + 256 + 4 * l);
        }
        while (p < R) {
            const int pn = p + 8;
            int c4n = 0;
            float4 nA = z4, nB = z4;
            if (pn < R) {
                c4n = c4beg(pn);
                const float* __restrict__ rn = Mb + (size_t)pn * PDIM;
                if (l >= c4n)                nA = *(const float4*)(rn + 4 * l);
                if (l < 36 && 64 + l >= c4n) nB = *(const float4*)(rn + 256 + 4 * l);
            }

            const float la = s_la[p];   // wave-uniform LDS broadcast
            float acc = 0.f;
            if (l >= c4) {
                float m0 = clamp1(fmaf(FORGET, cA.x, la * bA.x));
                float m1 = clamp1(fmaf(FORGET, cA.y, la * bA.y));
                float m2 = clamp1(fmaf(FORGET, cA.z, la * bA.z));
                float m3 = clamp1(fmaf(FORGET, cA.w, la * bA.w));
                acc = fmaf(m0, hA.x, fmaf(m1, hA.y, fmaf(m2, hA.z, m3 * hA.w)));
            }
            if (l < 36 && 64 + l >= c4) {
                float m0 = clamp1(fmaf(FORGET, cB.x, la * bB.x));
                float m1 = clamp1(fmaf(FORGET, cB.y, la * bB.y));
                float m2 = clamp1(fmaf(FORGET, cB.z, la * bB.z));
                float m3 = clamp1(fmaf(FORGET, cB.w, la * bB.w));
                acc = fmaf(m0, hB.x, fmaf(m1, hB.y, fmaf(m2, hB.z, fmaf(m3, hB.w, acc))));
            }

            const float tot = wave_sum(acc);
            if (l == 0) {
                hnew[p] = leaky_clip(fmaf(DECAY, hcur[p], tot));
            }

            p = pn; c4 = c4n; cA = nA; cB = nB;
        }

        // frozen rows carry through
        if (tid >= R && tid < PDIM) hnew[tid] = hcur[tid];
        __syncthreads();
        cur ^= 1;
    }

    if (tid < PDIM) {
        out[b * PDIM + tid] = s_h[cur][tid];
    }
}

extern "C" void kernel_launch(void* const* d_in, const int* in_sizes, int n_in,
                              void* d_out, int out_size, void* d_ws, size_t ws_size,
                              hipStream_t stream) {
    const float* M_prev = (const float*)d_in[0];
    const float* p_inf  = (const float*)d_in[1];
    const float* p_gen  = (const float*)d_in[2];
    const float* query  = (const float*)d_in[3];
    float* out = (float*)d_out;

    const int B = in_sizes[1] / PDIM;   // 512
    hipLaunchKernelGGL(hier_mem_kernel, dim3(B), dim3(512), 0, stream,
                       M_prev, p_inf, p_gen, query, out);
}